// Round 12
// baseline (381.893 us; speedup 1.0000x reference)
//
#include <hip/hip_runtime.h>

// SNN forward — conv1, conv2, fc1 on MFMA bf16 (3-way weight splits, fp32-grade).
// R12: graph-node reduction 13 -> 7. prep_all merges zero+3 weight preps;
//      BN finalizes folded into their consumer kernels (identical fp32 order);
//      reduce_lif+fc2 fused into fc_tail (spikes via LDS).

#define LIF_STEP(vv, xx, ss) do { \
    vv = fmaf((xx) - vv, 0.5f, vv); \
    ss = (vv >= 1.0f) ? 1.0f : 0.0f; \
    vv = (vv >= 1.0f) ? 0.0f : vv; \
  } while (0)

typedef __attribute__((ext_vector_type(8))) short short8;
typedef __attribute__((ext_vector_type(4))) float f32x4;

__device__ __forceinline__ float bf2f(unsigned short u) {
  return __uint_as_float(((unsigned)u) << 16);
}
__device__ __forceinline__ unsigned short f2bf(float f) {
  return (unsigned short)(__float_as_uint(f) >> 16);  // truncation split
}

// ---- workspace layout (float-slot offsets) ----
// pool1 bf16 [1024 tb][8 cg][16 py][16 px][8 ci_l] (reused as fc1 partials after conv2)
// pool2 bf16 [1024 tb][64 s][128 ci]
// preact f32 [1024 tb][16 row][128 co][16 col]
#define OFF_POOL1   0u
#define OFF_POOL2   8388608u
#define OFF_PRE     12582912u
#define OFF_STATS   46137344u   // f32 24,960
#define OFF_FC1S    46162304u   // (unused after R12 fc_tail fusion; kept for layout stability)
#define OFF_A2      46424448u   // bf16 3x[18 kc][128 co][4 q][8 j]
#define OFF_B1      46535040u   // bf16 3x[256 kc][256 o][4 q][8 j]
#define OFF_A1      49680768u   // bf16 3x[64 co][32 k]
// total 49,683,840 floats = 198.7 MB
// stats sublayout: s1p[64 sp][2][64] | s2p[64 sp][2][128]
#define ZERO_STATS 24576u

// ---- prep_all: zero stats (blocks 0..95) + prep_w1 (96..103) + prep_w2 (104..391)
//      + prep_b1 (392..775). One graph node instead of four. ----
__global__ __launch_bounds__(256) void prep_all(const float* __restrict__ w1,
    const float* __restrict__ w2, const float* __restrict__ wfc1,
    float* __restrict__ st, unsigned short* __restrict__ A1,
    unsigned short* __restrict__ A2, unsigned short* __restrict__ B1) {
  int bx = blockIdx.x;
  int tid = threadIdx.x;
  if (bx < 96) {
    unsigned i = bx * 256u + tid;
    if (i < ZERO_STATS) st[i] = 0.0f;
  } else if (bx < 104) {
    int i = (bx - 96) * 256 + tid;
    if (i < 2048) {
      int co = i >> 5, k = i & 31;
      float wv = 0.f;
      if (k < 27) {
        int tap = k / 3, ci = k - tap * 3;
        wv = w1[co * 27 + ci * 9 + tap];
      }
      unsigned short hi = f2bf(wv);
      float rem = wv - bf2f(hi);
      unsigned short lo = f2bf(rem);
      float rem2 = rem - bf2f(lo);
      A1[i] = hi;
      A1[2048 + i] = lo;
      A1[4096 + i] = f2bf(rem2);
    }
  } else if (bx < 392) {
    int i = (bx - 104) * 256 + tid;
    if (i < 73728) {
      int co = i / 576, r = i - co * 576;
      int ci = r / 9, t9 = r - ci * 9;
      int k = t9 * 64 + ci;
      int kc = k >> 5, q = (k >> 3) & 3, j = k & 7;
      int off = ((kc * 128 + co) * 4 + q) * 8 + j;
      float wv = w2[i];
      unsigned short hi = f2bf(wv);
      float rem = wv - bf2f(hi);
      unsigned short lo = f2bf(rem);
      float rem2 = rem - bf2f(lo);
      A2[off] = hi;
      A2[73728 + off] = lo;
      A2[147456 + off] = f2bf(rem2);
    }
  } else {
    __shared__ unsigned short sh[2][8192];
    int blk = bx - 392;        // 384 = sv*128 + opair
    int sv = blk >> 7, opair = blk & 127;
    for (int o_l = 0; o_l < 2; ++o_l) {
      for (int it = 0; it < 32; ++it) {
        int korig = tid + 256 * it;
        float wv = wfc1[(size_t)(opair * 2 + o_l) * 8192 + korig];
        unsigned short hi = f2bf(wv);
        float rem = wv - bf2f(hi);
        unsigned short lo = f2bf(rem);
        unsigned short pc = (sv == 0) ? hi : (sv == 1) ? lo : f2bf(rem - bf2f(lo));
        int k = (korig & 63) * 128 + (korig >> 6);
        sh[o_l][k] = pc;
      }
    }
    __syncthreads();
    unsigned short* outp = B1 + (size_t)sv * 2097152;
    for (int it = 0; it < 64; ++it) {
      int idx = tid + 256 * it;
      int kc = idx >> 6, r = idx & 63;
      int o_l = r >> 5, m = r & 31;
      outp[kc * 8192 + opair * 64 + r] = sh[o_l][kc * 32 + m];
    }
  }
}

// ---- conv1 pass 1 (MFMA im2col): stats only. (validated R9) ----
__global__ __launch_bounds__(256) void conv1_pass1_mfma(const float* __restrict__ x,
    const unsigned short* __restrict__ A1, float* __restrict__ s1p) {
  int b = blockIdx.x >> 3, yq = blockIdx.x & 7;
  int y0 = yq * 4;
  int sp = blockIdx.x & 63;
  int tid = threadIdx.x, wave = tid >> 6, lane = tid & 63;
  int xl = lane & 15, q = lane >> 4;
  __shared__ float xs[648];
  short8 A[3][4];
#pragma unroll
  for (int mt = 0; mt < 4; ++mt) {
    int aoff = (mt * 16 + xl) * 32 + q * 8;
    A[0][mt] = *(const short8*)(A1 + aoff);
    A[1][mt] = *(const short8*)(A1 + 2048 + aoff);
    A[2][mt] = *(const short8*)(A1 + 4096 + aoff);
  }
  int cb[8]; bool vld[8];
#pragma unroll
  for (int j = 0; j < 8; ++j) {
    int k = q * 8 + j;
    int tap = k / 3, ci = k - tap * 3;
    int dy = tap / 3, dx = tap - dy * 3;
    vld[j] = (k < 27);
    cb[j] = ci * 216 + (wave + dy) * 36 + dx + xl;
  }
  float s1[4][4], s2[4][4];
#pragma unroll
  for (int mt = 0; mt < 4; ++mt)
#pragma unroll
    for (int reg = 0; reg < 4; ++reg) { s1[mt][reg] = 0.f; s2[mt][reg] = 0.f; }

#pragma unroll 1
  for (int t = 0; t < 8; ++t) {
    int tb = t * 128 + b;
    const float* xb = x + tb * 3072;
    __syncthreads();
    for (int i = tid; i < 648; i += 256) {
      int ci = i / 216, r1 = i - ci * 216;
      int rr = r1 / 36, c = r1 - rr * 36;
      int gy = y0 - 1 + rr, gx = c - 1;
      xs[i] = ((unsigned)gy < 32u && (unsigned)gx < 32u) ? xb[(ci * 32 + gy) * 32 + gx] : 0.f;
    }
    __syncthreads();
    f32x4 acc[2][4];
#pragma unroll
    for (int tile = 0; tile < 2; ++tile)
#pragma unroll
      for (int mt = 0; mt < 4; ++mt) acc[tile][mt] = (f32x4){0.f, 0.f, 0.f, 0.f};
#pragma unroll
    for (int tile = 0; tile < 2; ++tile) {
      short8 Bh = (short8){0,0,0,0,0,0,0,0};
      short8 Bl = (short8){0,0,0,0,0,0,0,0};
      short8 Bll = (short8){0,0,0,0,0,0,0,0};
#pragma unroll
      for (int j = 0; j < 8; ++j) {
        float xv = vld[j] ? xs[cb[j] + tile * 16] : 0.f;
        unsigned short h = f2bf(xv);
        float r = xv - bf2f(h);
        unsigned short l = f2bf(r);
        float r2 = r - bf2f(l);
        Bh[j] = (short)h; Bl[j] = (short)l; Bll[j] = (short)f2bf(r2);
      }
#pragma unroll
      for (int mt = 0; mt < 4; ++mt) {
        f32x4 a = acc[tile][mt];
        a = __builtin_amdgcn_mfma_f32_16x16x32_bf16(A[0][mt], Bh, a, 0, 0, 0);
        a = __builtin_amdgcn_mfma_f32_16x16x32_bf16(A[1][mt], Bh, a, 0, 0, 0);
        a = __builtin_amdgcn_mfma_f32_16x16x32_bf16(A[2][mt], Bh, a, 0, 0, 0);
        a = __builtin_amdgcn_mfma_f32_16x16x32_bf16(A[0][mt], Bl, a, 0, 0, 0);
        a = __builtin_amdgcn_mfma_f32_16x16x32_bf16(A[1][mt], Bl, a, 0, 0, 0);
        a = __builtin_amdgcn_mfma_f32_16x16x32_bf16(A[2][mt], Bl, a, 0, 0, 0);
        a = __builtin_amdgcn_mfma_f32_16x16x32_bf16(A[0][mt], Bll, a, 0, 0, 0);
        a = __builtin_amdgcn_mfma_f32_16x16x32_bf16(A[1][mt], Bll, a, 0, 0, 0);
        acc[tile][mt] = a;
      }
    }
#pragma unroll
    for (int tile = 0; tile < 2; ++tile)
#pragma unroll
      for (int mt = 0; mt < 4; ++mt)
#pragma unroll
        for (int reg = 0; reg < 4; ++reg) {
          float val = acc[tile][mt][reg];
          s1[mt][reg] += val; s2[mt][reg] = fmaf(val, val, s2[mt][reg]);
        }
  }
#pragma unroll
  for (int mt = 0; mt < 4; ++mt)
#pragma unroll
    for (int reg = 0; reg < 4; ++reg) {
      float a1 = s1[mt][reg], a2 = s2[mt][reg];
#pragma unroll
      for (int off = 1; off < 16; off <<= 1) { a1 += __shfl_xor(a1, off); a2 += __shfl_xor(a2, off); }
      if (xl == 0) {
        int co = mt * 16 + q * 4 + reg;
        atomicAdd(&s1p[sp * 128 + co], a1);
        atomicAdd(&s1p[sp * 128 + 64 + co], a2);
      }
    }
}

// ---- conv1 pass 2 (MFMA im2col): fused BN1-finalize + conv+BN+LIF+pool. ----
// R12: finalize inlined (thread c<64 sums 64 sp in the SAME order as the old
// finalize_bn1 kernel -> bit-identical scale/shift; no separate dispatch).
__global__ __launch_bounds__(256) void conv1_fused_mfma(const float* __restrict__ x,
    const unsigned short* __restrict__ A1, const float* __restrict__ s1p,
    const float* __restrict__ g, const float* __restrict__ bb_,
    unsigned short* __restrict__ pool1) {
  int b = blockIdx.x >> 3, yq = blockIdx.x & 7;
  int y0 = yq * 4;
  int tid = threadIdx.x, wave = tid >> 6, lane = tid & 63;
  int xl = lane & 15, q = lane >> 4;
  __shared__ float xs[648];
  __shared__ unsigned short shout[4 * 16 * 72];
  __shared__ float scsh[128];   // scale[0..63] | shift[64..127]
  if (tid < 64) {
    int c = tid;
    float t1 = 0.f, t2 = 0.f;
#pragma unroll 8
    for (int sp = 0; sp < 64; ++sp) {
      t1 += s1p[sp * 128 + c];
      t2 += s1p[sp * 128 + 64 + c];
    }
    float mean = t1 * (1.0f / 1048576.0f);
    float var = fmaxf(t2 * (1.0f / 1048576.0f) - mean * mean, 0.0f);
    float rstd = rsqrtf(var + 1e-5f);
    float sc = g[c] * rstd;
    scsh[c] = sc;
    scsh[64 + c] = fmaf(-mean, sc, bb_[c]);
  }
  short8 A[3][4];
#pragma unroll
  for (int mt = 0; mt < 4; ++mt) {
    int aoff = (mt * 16 + xl) * 32 + q * 8;
    A[0][mt] = *(const short8*)(A1 + aoff);
    A[1][mt] = *(const short8*)(A1 + 2048 + aoff);
    A[2][mt] = *(const short8*)(A1 + 4096 + aoff);
  }
  int cb[8]; bool vld[8];
#pragma unroll
  for (int j = 0; j < 8; ++j) {
    int k = q * 8 + j;
    int tap = k / 3, ci = k - tap * 3;
    int dy = tap / 3, dx = tap - dy * 3;
    vld[j] = (k < 27);
    cb[j] = ci * 216 + (wave + dy) * 36 + dx + xl;
  }
  __syncthreads();   // scsh ready
  float scr[4][4], shr[4][4];
#pragma unroll
  for (int mt = 0; mt < 4; ++mt)
#pragma unroll
    for (int reg = 0; reg < 4; ++reg) {
      int co = mt * 16 + q * 4 + reg;
      scr[mt][reg] = scsh[co]; shr[mt][reg] = scsh[64 + co];
    }
  float v[2][4][4];
#pragma unroll
  for (int tile = 0; tile < 2; ++tile)
#pragma unroll
    for (int mt = 0; mt < 4; ++mt)
#pragma unroll
      for (int reg = 0; reg < 4; ++reg) v[tile][mt][reg] = 0.f;

#pragma unroll 1
  for (int t = 0; t < 8; ++t) {
    int tb = t * 128 + b;
    const float* xb = x + tb * 3072;
    __syncthreads();
    for (int i = tid; i < 648; i += 256) {
      int ci = i / 216, r1 = i - ci * 216;
      int rr = r1 / 36, c = r1 - rr * 36;
      int gy = y0 - 1 + rr, gx = c - 1;
      xs[i] = ((unsigned)gy < 32u && (unsigned)gx < 32u) ? xb[(ci * 32 + gy) * 32 + gx] : 0.f;
    }
    __syncthreads();
    f32x4 acc[2][4];
#pragma unroll
    for (int tile = 0; tile < 2; ++tile)
#pragma unroll
      for (int mt = 0; mt < 4; ++mt) acc[tile][mt] = (f32x4){0.f, 0.f, 0.f, 0.f};
#pragma unroll
    for (int tile = 0; tile < 2; ++tile) {
      short8 Bh = (short8){0,0,0,0,0,0,0,0};
      short8 Bl = (short8){0,0,0,0,0,0,0,0};
      short8 Bll = (short8){0,0,0,0,0,0,0,0};
#pragma unroll
      for (int j = 0; j < 8; ++j) {
        float xv = vld[j] ? xs[cb[j] + tile * 16] : 0.f;
        unsigned short h = f2bf(xv);
        float r = xv - bf2f(h);
        unsigned short l = f2bf(r);
        float r2 = r - bf2f(l);
        Bh[j] = (short)h; Bl[j] = (short)l; Bll[j] = (short)f2bf(r2);
      }
#pragma unroll
      for (int mt = 0; mt < 4; ++mt) {
        f32x4 a = acc[tile][mt];
        a = __builtin_amdgcn_mfma_f32_16x16x32_bf16(A[0][mt], Bh, a, 0, 0, 0);
        a = __builtin_amdgcn_mfma_f32_16x16x32_bf16(A[1][mt], Bh, a, 0, 0, 0);
        a = __builtin_amdgcn_mfma_f32_16x16x32_bf16(A[2][mt], Bh, a, 0, 0, 0);
        a = __builtin_amdgcn_mfma_f32_16x16x32_bf16(A[0][mt], Bl, a, 0, 0, 0);
        a = __builtin_amdgcn_mfma_f32_16x16x32_bf16(A[1][mt], Bl, a, 0, 0, 0);
        a = __builtin_amdgcn_mfma_f32_16x16x32_bf16(A[2][mt], Bl, a, 0, 0, 0);
        a = __builtin_amdgcn_mfma_f32_16x16x32_bf16(A[0][mt], Bll, a, 0, 0, 0);
        a = __builtin_amdgcn_mfma_f32_16x16x32_bf16(A[1][mt], Bll, a, 0, 0, 0);
        acc[tile][mt] = a;
      }
    }
#pragma unroll
    for (int mt = 0; mt < 4; ++mt)
#pragma unroll
      for (int rp = 0; rp < 2; ++rp) {
        float hp[2][2];
#pragma unroll
        for (int tile = 0; tile < 2; ++tile)
#pragma unroll
          for (int e = 0; e < 2; ++e) {
            int reg = rp * 2 + e;
            float xv = fmaf(acc[tile][mt][reg], scr[mt][reg], shr[mt][reg]);
            float spk;
            LIF_STEP(v[tile][mt][reg], xv, spk);
            hp[tile][e] = spk + __shfl_xor(spk, 1);
          }
        int tw = xl & 1;
        float h0 = tw ? hp[1][0] : hp[0][0];
        float h1 = tw ? hp[1][1] : hp[0][1];
        unsigned u = (unsigned)f2bf(h0) | ((unsigned)f2bf(h1) << 16);
        int pp = tw * 8 + (xl >> 1);
        *(unsigned*)&shout[(wave * 16 + pp) * 72 + mt * 16 + q * 4 + rp * 2] = u;
      }
    __syncthreads();
    {
      int cg = tid >> 5, py_l = (tid >> 4) & 1, px = tid & 15;
      uint4 ua = *(const uint4*)&shout[((2 * py_l) * 16 + px) * 72 + cg * 8];
      uint4 ub = *(const uint4*)&shout[((2 * py_l + 1) * 16 + px) * 72 + cg * 8];
      const unsigned* pa = (const unsigned*)&ua;
      const unsigned* pb = (const unsigned*)&ub;
      unsigned o[4];
#pragma unroll
      for (int e = 0; e < 4; ++e) {
        float a0 = bf2f((unsigned short)(pa[e] & 0xffffu)), a1 = bf2f((unsigned short)(pa[e] >> 16));
        float b0 = bf2f((unsigned short)(pb[e] & 0xffffu)), b1 = bf2f((unsigned short)(pb[e] >> 16));
        o[e] = (unsigned)f2bf(0.25f * (a0 + b0)) | ((unsigned)f2bf(0.25f * (a1 + b1)) << 16);
      }
      int py = yq * 2 + py_l;
      *(uint4*)(pool1 + (size_t)tb * 16384 + cg * 2048 + (py * 16 + px) * 8) =
          make_uint4(o[0], o[1], o[2], o[3]);
    }
  }
}

// ---- conv2 helpers ----
__device__ __forceinline__ void c2_load_a(const unsigned short* __restrict__ A2, int kc,
                                          int m0, int xl, int q, short8 (&a)[2][3]) {
#pragma unroll
  for (int mt = 0; mt < 2; ++mt) {
    int aoff = ((kc * 128 + m0 + mt * 16 + xl) * 4 + q) * 8;
    a[mt][0] = *(const short8*)(A2 + aoff);
    a[mt][1] = *(const short8*)(A2 + 73728 + aoff);
    a[mt][2] = *(const short8*)(A2 + 147456 + aoff);
  }
}
__device__ __forceinline__ void c2_step8(const unsigned short* __restrict__ simg, int kc,
                                         int xl, int q, short8 (&a)[2][3], f32x4 (&acc)[2][8]) {
  int tap = kc >> 1;
  int dy = tap / 3, dx = tap - dy * 3;
  int cgq = (kc & 1) * 4 + q;
#pragma unroll
  for (int yl = 0; yl < 8; ++yl) {
    int baddr = (((yl + dy) * 8 + cgq) * 18 + (xl + dx)) * 8;
    short8 bb = *(const short8*)(simg + baddr);
#pragma unroll
    for (int mt = 0; mt < 2; ++mt) {
      acc[mt][yl] = __builtin_amdgcn_mfma_f32_16x16x32_bf16(a[mt][0], bb, acc[mt][yl], 0, 0, 0);
      acc[mt][yl] = __builtin_amdgcn_mfma_f32_16x16x32_bf16(a[mt][1], bb, acc[mt][yl], 0, 0, 0);
      acc[mt][yl] = __builtin_amdgcn_mfma_f32_16x16x32_bf16(a[mt][2], bb, acc[mt][yl], 0, 0, 0);
    }
  }
}

// ---- conv2 (MFMA, single pass): stats + fp32 preact store. (validated R11) ----
__global__ __launch_bounds__(256, 2) void conv2_store_mfma(const unsigned short* __restrict__ pool1,
    const unsigned short* __restrict__ A2, float* __restrict__ preact, float* __restrict__ s2p) {
  int bx = blockIdx.x;
  int tb = bx >> 1, half = bx & 1;
  int sp = bx & 63;
  __shared__ unsigned short simg[10 * 8 * 18 * 8];
  int tid = threadIdx.x;
  const unsigned* src = (const unsigned*)(pool1 + (size_t)tb * 16384);
  unsigned* dstw = (unsigned*)simg;
  for (int i = tid; i < 5760; i += 256) {
    int cp = i & 3, rest = i >> 2;
    int jj = rest / 18, xx = rest - jj * 18;
    int cg = jj & 7, row_l = jj >> 3;
    int yi = half * 8 - 1 + row_l, gx = xx - 1;
    unsigned val = 0u;
    if ((unsigned)yi < 16u && (unsigned)gx < 16u)
      val = src[cg * 1024 + yi * 64 + gx * 4 + cp];
    dstw[i] = val;
  }
  __syncthreads();

  int wave = tid >> 6, lane = tid & 63;
  int xl = lane & 15, q = lane >> 4;
  int m0 = wave * 32;
  f32x4 acc[2][8];
#pragma unroll
  for (int mt = 0; mt < 2; ++mt)
#pragma unroll
    for (int yl = 0; yl < 8; ++yl) acc[mt][yl] = (f32x4){0.f, 0.f, 0.f, 0.f};

  short8 aA[2][3], aB[2][3];
  c2_load_a(A2, 0, m0, xl, q, aA);
#pragma unroll 1
  for (int kc = 0; kc < 18; kc += 2) {
    c2_load_a(A2, kc + 1, m0, xl, q, aB);
    c2_step8(simg, kc, xl, q, aA, acc);
    if (kc + 2 < 18) c2_load_a(A2, kc + 2, m0, xl, q, aA);
    c2_step8(simg, kc + 1, xl, q, aB, acc);
  }

  float* pre = preact + (size_t)tb * 32768;
#pragma unroll
  for (int mt = 0; mt < 2; ++mt)
#pragma unroll
    for (int reg = 0; reg < 4; ++reg) {
      int co = m0 + mt * 16 + q * 4 + reg;
      float s1 = 0.f, s2 = 0.f;
#pragma unroll
      for (int yl = 0; yl < 8; ++yl) {
        float val = acc[mt][yl][reg];
        int row = half * 8 + yl;
        pre[(row * 128 + co) * 16 + xl] = val;
        s1 += val; s2 = fmaf(val, val, s2);
      }
#pragma unroll
      for (int off = 1; off < 16; off <<= 1) {
        s1 += __shfl_xor(s1, off); s2 += __shfl_xor(s2, off);
      }
      if (xl == 0) {
        atomicAdd(&s2p[sp * 256 + co], s1);
        atomicAdd(&s2p[sp * 256 + 128 + co], s2);
      }
    }
}

// ---- BN2-finalize (inlined) + LIF + pool over stored preact. ----
__global__ __launch_bounds__(256) void bn2_lif_pool(const float* __restrict__ pre,
    const float* __restrict__ s2p, const float* __restrict__ g, const float* __restrict__ bb_,
    unsigned short* __restrict__ pool2) {
  int b = blockIdx.x >> 3, py = blockIdx.x & 7;
  int tid = threadIdx.x;
  int co = tid >> 1, half = tid & 1;
  __shared__ unsigned short shout[8 * 136];
  __shared__ float scsh[256];   // scale[0..127] | shift[128..255]
  if (tid < 128) {
    int c = tid;
    float t1 = 0.f, t2 = 0.f;
#pragma unroll 8
    for (int sp = 0; sp < 64; ++sp) {
      t1 += s2p[sp * 256 + c];
      t2 += s2p[sp * 256 + 128 + c];
    }
    float mean = t1 * (1.0f / 262144.0f);
    float var = fmaxf(t2 * (1.0f / 262144.0f) - mean * mean, 0.0f);
    float rstd = rsqrtf(var + 1e-5f);
    float sc = g[c] * rstd;
    scsh[c] = sc;
    scsh[128 + c] = fmaf(-mean, sc, bb_[c]);
  }
  __syncthreads();
  float sc = scsh[co], sh = scsh[128 + co];
  float v[4][4];
#pragma unroll
  for (int p = 0; p < 4; ++p)
#pragma unroll
    for (int e = 0; e < 4; ++e) v[p][e] = 0.f;

#pragma unroll 1
  for (int t = 0; t < 8; ++t) {
    const float* base = pre + ((size_t)((t * 128 + b) * 16 + 2 * py)) * 2048 + co * 16 + half * 8;
    __syncthreads();
    float4 r0a = *(const float4*)(base);
    float4 r0b = *(const float4*)(base + 4);
    float4 r1a = *(const float4*)(base + 2048);
    float4 r1b = *(const float4*)(base + 2048 + 4);
    float p00[4] = {r0a.x, r0a.z, r0b.x, r0b.z};
    float p01[4] = {r0a.y, r0a.w, r0b.y, r0b.w};
    float p10[4] = {r1a.x, r1a.z, r1b.x, r1b.z};
    float p11[4] = {r1a.y, r1a.w, r1b.y, r1b.w};
#pragma unroll
    for (int p = 0; p < 4; ++p) {
      float s00, s01, s10, s11, xv;
      xv = fmaf(p00[p], sc, sh); LIF_STEP(v[p][0], xv, s00);
      xv = fmaf(p01[p], sc, sh); LIF_STEP(v[p][1], xv, s01);
      xv = fmaf(p10[p], sc, sh); LIF_STEP(v[p][2], xv, s10);
      xv = fmaf(p11[p], sc, sh); LIF_STEP(v[p][3], xv, s11);
      shout[(half * 4 + p) * 136 + co] = f2bf(0.25f * (s00 + s01 + s10 + s11));
    }
    __syncthreads();
    {
      int s_l = tid >> 5, ci4 = (tid & 31) * 4;
      uint2 vv = *(const uint2*)&shout[s_l * 136 + ci4];
      *(uint2*)(pool2 + ((size_t)(t * 128 + b) * 64 + py * 8 + s_l) * 128 + ci4) = vv;
    }
  }
}

// ---- fc1 (MFMA): partial[kb][o 256][tb 1024], split-K=16, 2 kc/barrier. (validated R11) ----
__global__ __launch_bounds__(256, 2) void fc1_mfma(const unsigned short* __restrict__ pool2,
    const unsigned short* __restrict__ B1, float* __restrict__ partial) {
  int bx = blockIdx.x;
  int t_o = bx & 1, tbt = (bx >> 1) & 15, kb = bx >> 5;
  int tid = threadIdx.x, wave = tid >> 6, lane = tid & 63;
  int xl = lane & 15, q = lane >> 4;
  int m0 = t_o * 128 + wave * 32;
  int n0 = tbt * 64;
  __shared__ unsigned short sB[2][64 * 42];
  f32x4 acc[2][4];
#pragma unroll
  for (int mt = 0; mt < 2; ++mt)
#pragma unroll
    for (int nt = 0; nt < 4; ++nt) acc[mt][nt] = (f32x4){0.f, 0.f, 0.f, 0.f};

#pragma unroll 1
  for (int kc0 = 0; kc0 < 16; kc0 += 2) {
    int kc = kb * 16 + kc0;
    __syncthreads();
    {
      int tb_l = tid >> 2, kq = tid & 3;
      const unsigned short* srcp = pool2 + (size_t)(n0 + tb_l) * 8192 + kc * 32 + kq * 8;
      uint4 v0 = *(const uint4*)(srcp);
      uint4 v1 = *(const uint4*)(srcp + 32);
      *(uint4*)(sB[0] + tb_l * 42 + kq * 8) = v0;
      *(uint4*)(sB[1] + tb_l * 42 + kq * 8) = v1;
    }
    __syncthreads();
#pragma unroll
    for (int sub = 0; sub < 2; ++sub) {
      int kcs = kc + sub;
      short8 a[2][3];
#pragma unroll
      for (int mt = 0; mt < 2; ++mt) {
        int aoff = ((kcs * 256 + m0 + mt * 16 + xl) * 4 + q) * 8;
        a[mt][0] = *(const short8*)(B1 + aoff);
        a[mt][1] = *(const short8*)(B1 + 2097152 + aoff);
        a[mt][2] = *(const short8*)(B1 + 4194304 + aoff);
      }
#pragma unroll
      for (int nt = 0; nt < 4; ++nt) {
        short8 bb = *(const short8*)(sB[sub] + (nt * 16 + xl) * 42 + q * 8);
#pragma unroll
        for (int mt = 0; mt < 2; ++mt) {
          acc[mt][nt] = __builtin_amdgcn_mfma_f32_16x16x32_bf16(a[mt][0], bb, acc[mt][nt], 0, 0, 0);
          acc[mt][nt] = __builtin_amdgcn_mfma_f32_16x16x32_bf16(a[mt][1], bb, acc[mt][nt], 0, 0, 0);
          acc[mt][nt] = __builtin_amdgcn_mfma_f32_16x16x32_bf16(a[mt][2], bb, acc[mt][nt], 0, 0, 0);
        }
      }
    }
  }
#pragma unroll
  for (int mt = 0; mt < 2; ++mt)
#pragma unroll
    for (int nt = 0; nt < 4; ++nt)
#pragma unroll
      for (int reg = 0; reg < 4; ++reg) {
        int o = m0 + mt * 16 + q * 4 + reg;
        partial[((size_t)kb * 256 + o) * 1024 + n0 + nt * 16 + xl] = acc[mt][nt][reg];
      }
}

// ---- fc_tail: reduce partials + LIF + fc2 + bias, fused. Block = b (grid 128). ----
// Same summation orders as the old reduce_lif (kb ascending) and fc2 (k ascending).
__global__ __launch_bounds__(256) void fc_tail(const float* __restrict__ partial,
    const float* __restrict__ w2, const float* __restrict__ bias, float* __restrict__ outp) {
  int b = blockIdx.x;
  int o = threadIdx.x;
  __shared__ float sp_lds[8 * 256];
  float v = 0.f;
#pragma unroll 1
  for (int t = 0; t < 8; ++t) {
    float xv = 0.f;
#pragma unroll
    for (int kb = 0; kb < 16; ++kb)
      xv += partial[((size_t)kb * 256 + o) * 1024 + t * 128 + b];
    float s;
    LIF_STEP(v, xv, s);
    sp_lds[t * 256 + o] = s;
  }
  __syncthreads();
  if (threadIdx.x < 80) {
    int t = threadIdx.x & 7, o10 = threadIdx.x >> 3;
    float a = bias[o10];
    const float* wr = w2 + o10 * 256;
    const float* sv = sp_lds + t * 256;
#pragma unroll 8
    for (int k = 0; k < 256; ++k) a = fmaf(sv[k], wr[k], a);
    outp[(t * 128 + b) * 10 + o10] = a;
  }
}

extern "C" void kernel_launch(void* const* d_in, const int* in_sizes, int n_in,
                              void* d_out, int out_size, void* d_ws, size_t ws_size,
                              hipStream_t stream) {
  (void)in_sizes; (void)n_in; (void)out_size; (void)ws_size;
  const float* x_seq   = (const float*)d_in[0];
  const float* conv1_w = (const float*)d_in[1];
  const float* bn1_g   = (const float*)d_in[2];
  const float* bn1_b   = (const float*)d_in[3];
  const float* conv2_w = (const float*)d_in[4];
  const float* bn2_g   = (const float*)d_in[5];
  const float* bn2_b   = (const float*)d_in[6];
  const float* fc1_w   = (const float*)d_in[7];
  const float* fc2_w   = (const float*)d_in[8];
  const float* fc2_b   = (const float*)d_in[9];
  float* out = (float*)d_out;
  float* ws  = (float*)d_ws;

  unsigned short* pool1 = (unsigned short*)(ws + OFF_POOL1);
  float* fc1_part = ws + OFF_POOL1;              // pool1 dead after conv2_store
  unsigned short* pool2 = (unsigned short*)(ws + OFF_POOL2);
  float* preact  = ws + OFF_PRE;
  unsigned short* A2 = (unsigned short*)(ws + OFF_A2);
  unsigned short* B1 = (unsigned short*)(ws + OFF_B1);
  unsigned short* A1 = (unsigned short*)(ws + OFF_A1);
  float* st      = ws + OFF_STATS;
  float* s1p    = st;            // [64 sp][2][64]
  float* s2p    = st + 8192;     // [64 sp][2][128]

  // 1. zero stats + all three weight preps (one node)
  prep_all<<<776, 256, 0, stream>>>(conv1_w, conv2_w, fc1_w, st, A1, A2, B1);
  // 2. conv1 stats
  conv1_pass1_mfma<<<1024, 256, 0, stream>>>(x_seq, A1, s1p);
  // 3. conv1 fused (BN1 finalize inlined)
  conv1_fused_mfma<<<1024, 256, 0, stream>>>(x_seq, A1, s1p, bn1_g, bn1_b, pool1);
  // 4. conv2 single pass: stats + preact
  conv2_store_mfma<<<2048, 256, 0, stream>>>(pool1, A2, preact, s2p);
  // 5. BN2 finalize (inlined) + LIF + pool
  bn2_lif_pool<<<1024, 256, 0, stream>>>(preact, s2p, bn2_g, bn2_b, pool2);
  // 6. fc1 split-K partials
  fc1_mfma<<<512, 256, 0, stream>>>(pool2, B1, fc1_part);
  // 7. reduce + LIF + fc2 + bias (one node)
  fc_tail<<<128, 256, 0, stream>>>(fc1_part, fc2_w, fc2_b, out);
}

// Round 13
// 351.157 us; speedup vs baseline: 1.0875x; 1.0875x over previous
//
#include <hip/hip_runtime.h>

// SNN forward — conv1, conv2, fc1 on MFMA bf16 (3-way weight splits, fp32-grade).
// R13: revert fc_tail fusion (uncoalesced reads caused the R12 regression) ->
//      validated coalesced reduce_lif + fc2. Keep prep_all merge + inlined
//      BN finalizes (8 graph nodes).

#define LIF_STEP(vv, xx, ss) do { \
    vv = fmaf((xx) - vv, 0.5f, vv); \
    ss = (vv >= 1.0f) ? 1.0f : 0.0f; \
    vv = (vv >= 1.0f) ? 0.0f : vv; \
  } while (0)

typedef __attribute__((ext_vector_type(8))) short short8;
typedef __attribute__((ext_vector_type(4))) float f32x4;

__device__ __forceinline__ float bf2f(unsigned short u) {
  return __uint_as_float(((unsigned)u) << 16);
}
__device__ __forceinline__ unsigned short f2bf(float f) {
  return (unsigned short)(__float_as_uint(f) >> 16);  // truncation split
}

// ---- workspace layout (float-slot offsets) ----
#define OFF_POOL1   0u          // pool1 bf16 (reused as fc1 partials after conv2)
#define OFF_POOL2   8388608u    // pool2 bf16 [1024 tb][64 s][128 ci]
#define OFF_PRE     12582912u   // preact f32 [1024 tb][16 row][128 co][16 col]
#define OFF_STATS   46137344u   // f32 24,960
#define OFF_FC1S    46162304u   // f32 262,144 : fc1 spikes [t][b][o]
#define OFF_A2      46424448u   // bf16 3x[18 kc][128 co][4 q][8 j]
#define OFF_B1      46535040u   // bf16 3x[256 kc][256 o][4 q][8 j]
#define OFF_A1      49680768u   // bf16 3x[64 co][32 k]
// total 49,683,840 floats = 198.7 MB
// stats sublayout: s1p[64 sp][2][64] | s2p[64 sp][2][128]
#define ZERO_STATS 24576u

// ---- prep_all: zero stats (blocks 0..95) + prep_w1 (96..103) + prep_w2 (104..391)
//      + prep_b1 (392..775). ----
__global__ __launch_bounds__(256) void prep_all(const float* __restrict__ w1,
    const float* __restrict__ w2, const float* __restrict__ wfc1,
    float* __restrict__ st, unsigned short* __restrict__ A1,
    unsigned short* __restrict__ A2, unsigned short* __restrict__ B1) {
  int bx = blockIdx.x;
  int tid = threadIdx.x;
  if (bx < 96) {
    unsigned i = bx * 256u + tid;
    if (i < ZERO_STATS) st[i] = 0.0f;
  } else if (bx < 104) {
    int i = (bx - 96) * 256 + tid;
    if (i < 2048) {
      int co = i >> 5, k = i & 31;
      float wv = 0.f;
      if (k < 27) {
        int tap = k / 3, ci = k - tap * 3;
        wv = w1[co * 27 + ci * 9 + tap];
      }
      unsigned short hi = f2bf(wv);
      float rem = wv - bf2f(hi);
      unsigned short lo = f2bf(rem);
      float rem2 = rem - bf2f(lo);
      A1[i] = hi;
      A1[2048 + i] = lo;
      A1[4096 + i] = f2bf(rem2);
    }
  } else if (bx < 392) {
    int i = (bx - 104) * 256 + tid;
    if (i < 73728) {
      int co = i / 576, r = i - co * 576;
      int ci = r / 9, t9 = r - ci * 9;
      int k = t9 * 64 + ci;
      int kc = k >> 5, q = (k >> 3) & 3, j = k & 7;
      int off = ((kc * 128 + co) * 4 + q) * 8 + j;
      float wv = w2[i];
      unsigned short hi = f2bf(wv);
      float rem = wv - bf2f(hi);
      unsigned short lo = f2bf(rem);
      float rem2 = rem - bf2f(lo);
      A2[off] = hi;
      A2[73728 + off] = lo;
      A2[147456 + off] = f2bf(rem2);
    }
  } else {
    __shared__ unsigned short sh[2][8192];
    int blk = bx - 392;        // 384 = sv*128 + opair
    int sv = blk >> 7, opair = blk & 127;
    for (int o_l = 0; o_l < 2; ++o_l) {
      for (int it = 0; it < 32; ++it) {
        int korig = tid + 256 * it;
        float wv = wfc1[(size_t)(opair * 2 + o_l) * 8192 + korig];
        unsigned short hi = f2bf(wv);
        float rem = wv - bf2f(hi);
        unsigned short lo = f2bf(rem);
        unsigned short pc = (sv == 0) ? hi : (sv == 1) ? lo : f2bf(rem - bf2f(lo));
        int k = (korig & 63) * 128 + (korig >> 6);
        sh[o_l][k] = pc;
      }
    }
    __syncthreads();
    unsigned short* outp = B1 + (size_t)sv * 2097152;
    for (int it = 0; it < 64; ++it) {
      int idx = tid + 256 * it;
      int kc = idx >> 6, r = idx & 63;
      int o_l = r >> 5, m = r & 31;
      outp[kc * 8192 + opair * 64 + r] = sh[o_l][kc * 32 + m];
    }
  }
}

// ---- conv1 pass 1 (MFMA im2col): stats only. (validated R9) ----
__global__ __launch_bounds__(256) void conv1_pass1_mfma(const float* __restrict__ x,
    const unsigned short* __restrict__ A1, float* __restrict__ s1p) {
  int b = blockIdx.x >> 3, yq = blockIdx.x & 7;
  int y0 = yq * 4;
  int sp = blockIdx.x & 63;
  int tid = threadIdx.x, wave = tid >> 6, lane = tid & 63;
  int xl = lane & 15, q = lane >> 4;
  __shared__ float xs[648];
  short8 A[3][4];
#pragma unroll
  for (int mt = 0; mt < 4; ++mt) {
    int aoff = (mt * 16 + xl) * 32 + q * 8;
    A[0][mt] = *(const short8*)(A1 + aoff);
    A[1][mt] = *(const short8*)(A1 + 2048 + aoff);
    A[2][mt] = *(const short8*)(A1 + 4096 + aoff);
  }
  int cb[8]; bool vld[8];
#pragma unroll
  for (int j = 0; j < 8; ++j) {
    int k = q * 8 + j;
    int tap = k / 3, ci = k - tap * 3;
    int dy = tap / 3, dx = tap - dy * 3;
    vld[j] = (k < 27);
    cb[j] = ci * 216 + (wave + dy) * 36 + dx + xl;
  }
  float s1[4][4], s2[4][4];
#pragma unroll
  for (int mt = 0; mt < 4; ++mt)
#pragma unroll
    for (int reg = 0; reg < 4; ++reg) { s1[mt][reg] = 0.f; s2[mt][reg] = 0.f; }

#pragma unroll 1
  for (int t = 0; t < 8; ++t) {
    int tb = t * 128 + b;
    const float* xb = x + tb * 3072;
    __syncthreads();
    for (int i = tid; i < 648; i += 256) {
      int ci = i / 216, r1 = i - ci * 216;
      int rr = r1 / 36, c = r1 - rr * 36;
      int gy = y0 - 1 + rr, gx = c - 1;
      xs[i] = ((unsigned)gy < 32u && (unsigned)gx < 32u) ? xb[(ci * 32 + gy) * 32 + gx] : 0.f;
    }
    __syncthreads();
    f32x4 acc[2][4];
#pragma unroll
    for (int tile = 0; tile < 2; ++tile)
#pragma unroll
      for (int mt = 0; mt < 4; ++mt) acc[tile][mt] = (f32x4){0.f, 0.f, 0.f, 0.f};
#pragma unroll
    for (int tile = 0; tile < 2; ++tile) {
      short8 Bh = (short8){0,0,0,0,0,0,0,0};
      short8 Bl = (short8){0,0,0,0,0,0,0,0};
      short8 Bll = (short8){0,0,0,0,0,0,0,0};
#pragma unroll
      for (int j = 0; j < 8; ++j) {
        float xv = vld[j] ? xs[cb[j] + tile * 16] : 0.f;
        unsigned short h = f2bf(xv);
        float r = xv - bf2f(h);
        unsigned short l = f2bf(r);
        float r2 = r - bf2f(l);
        Bh[j] = (short)h; Bl[j] = (short)l; Bll[j] = (short)f2bf(r2);
      }
#pragma unroll
      for (int mt = 0; mt < 4; ++mt) {
        f32x4 a = acc[tile][mt];
        a = __builtin_amdgcn_mfma_f32_16x16x32_bf16(A[0][mt], Bh, a, 0, 0, 0);
        a = __builtin_amdgcn_mfma_f32_16x16x32_bf16(A[1][mt], Bh, a, 0, 0, 0);
        a = __builtin_amdgcn_mfma_f32_16x16x32_bf16(A[2][mt], Bh, a, 0, 0, 0);
        a = __builtin_amdgcn_mfma_f32_16x16x32_bf16(A[0][mt], Bl, a, 0, 0, 0);
        a = __builtin_amdgcn_mfma_f32_16x16x32_bf16(A[1][mt], Bl, a, 0, 0, 0);
        a = __builtin_amdgcn_mfma_f32_16x16x32_bf16(A[2][mt], Bl, a, 0, 0, 0);
        a = __builtin_amdgcn_mfma_f32_16x16x32_bf16(A[0][mt], Bll, a, 0, 0, 0);
        a = __builtin_amdgcn_mfma_f32_16x16x32_bf16(A[1][mt], Bll, a, 0, 0, 0);
        acc[tile][mt] = a;
      }
    }
#pragma unroll
    for (int tile = 0; tile < 2; ++tile)
#pragma unroll
      for (int mt = 0; mt < 4; ++mt)
#pragma unroll
        for (int reg = 0; reg < 4; ++reg) {
          float val = acc[tile][mt][reg];
          s1[mt][reg] += val; s2[mt][reg] = fmaf(val, val, s2[mt][reg]);
        }
  }
#pragma unroll
  for (int mt = 0; mt < 4; ++mt)
#pragma unroll
    for (int reg = 0; reg < 4; ++reg) {
      float a1 = s1[mt][reg], a2 = s2[mt][reg];
#pragma unroll
      for (int off = 1; off < 16; off <<= 1) { a1 += __shfl_xor(a1, off); a2 += __shfl_xor(a2, off); }
      if (xl == 0) {
        int co = mt * 16 + q * 4 + reg;
        atomicAdd(&s1p[sp * 128 + co], a1);
        atomicAdd(&s1p[sp * 128 + 64 + co], a2);
      }
    }
}

// ---- conv1 pass 2 (MFMA im2col): fused BN1-finalize + conv+BN+LIF+pool. ----
__global__ __launch_bounds__(256) void conv1_fused_mfma(const float* __restrict__ x,
    const unsigned short* __restrict__ A1, const float* __restrict__ s1p,
    const float* __restrict__ g, const float* __restrict__ bb_,
    unsigned short* __restrict__ pool1) {
  int b = blockIdx.x >> 3, yq = blockIdx.x & 7;
  int y0 = yq * 4;
  int tid = threadIdx.x, wave = tid >> 6, lane = tid & 63;
  int xl = lane & 15, q = lane >> 4;
  __shared__ float xs[648];
  __shared__ unsigned short shout[4 * 16 * 72];
  __shared__ float scsh[128];   // scale[0..63] | shift[64..127]
  if (tid < 64) {
    int c = tid;
    float t1 = 0.f, t2 = 0.f;
#pragma unroll 8
    for (int sp = 0; sp < 64; ++sp) {
      t1 += s1p[sp * 128 + c];
      t2 += s1p[sp * 128 + 64 + c];
    }
    float mean = t1 * (1.0f / 1048576.0f);
    float var = fmaxf(t2 * (1.0f / 1048576.0f) - mean * mean, 0.0f);
    float rstd = rsqrtf(var + 1e-5f);
    float sc = g[c] * rstd;
    scsh[c] = sc;
    scsh[64 + c] = fmaf(-mean, sc, bb_[c]);
  }
  short8 A[3][4];
#pragma unroll
  for (int mt = 0; mt < 4; ++mt) {
    int aoff = (mt * 16 + xl) * 32 + q * 8;
    A[0][mt] = *(const short8*)(A1 + aoff);
    A[1][mt] = *(const short8*)(A1 + 2048 + aoff);
    A[2][mt] = *(const short8*)(A1 + 4096 + aoff);
  }
  int cb[8]; bool vld[8];
#pragma unroll
  for (int j = 0; j < 8; ++j) {
    int k = q * 8 + j;
    int tap = k / 3, ci = k - tap * 3;
    int dy = tap / 3, dx = tap - dy * 3;
    vld[j] = (k < 27);
    cb[j] = ci * 216 + (wave + dy) * 36 + dx + xl;
  }
  __syncthreads();   // scsh ready
  float scr[4][4], shr[4][4];
#pragma unroll
  for (int mt = 0; mt < 4; ++mt)
#pragma unroll
    for (int reg = 0; reg < 4; ++reg) {
      int co = mt * 16 + q * 4 + reg;
      scr[mt][reg] = scsh[co]; shr[mt][reg] = scsh[64 + co];
    }
  float v[2][4][4];
#pragma unroll
  for (int tile = 0; tile < 2; ++tile)
#pragma unroll
    for (int mt = 0; mt < 4; ++mt)
#pragma unroll
      for (int reg = 0; reg < 4; ++reg) v[tile][mt][reg] = 0.f;

#pragma unroll 1
  for (int t = 0; t < 8; ++t) {
    int tb = t * 128 + b;
    const float* xb = x + tb * 3072;
    __syncthreads();
    for (int i = tid; i < 648; i += 256) {
      int ci = i / 216, r1 = i - ci * 216;
      int rr = r1 / 36, c = r1 - rr * 36;
      int gy = y0 - 1 + rr, gx = c - 1;
      xs[i] = ((unsigned)gy < 32u && (unsigned)gx < 32u) ? xb[(ci * 32 + gy) * 32 + gx] : 0.f;
    }
    __syncthreads();
    f32x4 acc[2][4];
#pragma unroll
    for (int tile = 0; tile < 2; ++tile)
#pragma unroll
      for (int mt = 0; mt < 4; ++mt) acc[tile][mt] = (f32x4){0.f, 0.f, 0.f, 0.f};
#pragma unroll
    for (int tile = 0; tile < 2; ++tile) {
      short8 Bh = (short8){0,0,0,0,0,0,0,0};
      short8 Bl = (short8){0,0,0,0,0,0,0,0};
      short8 Bll = (short8){0,0,0,0,0,0,0,0};
#pragma unroll
      for (int j = 0; j < 8; ++j) {
        float xv = vld[j] ? xs[cb[j] + tile * 16] : 0.f;
        unsigned short h = f2bf(xv);
        float r = xv - bf2f(h);
        unsigned short l = f2bf(r);
        float r2 = r - bf2f(l);
        Bh[j] = (short)h; Bl[j] = (short)l; Bll[j] = (short)f2bf(r2);
      }
#pragma unroll
      for (int mt = 0; mt < 4; ++mt) {
        f32x4 a = acc[tile][mt];
        a = __builtin_amdgcn_mfma_f32_16x16x32_bf16(A[0][mt], Bh, a, 0, 0, 0);
        a = __builtin_amdgcn_mfma_f32_16x16x32_bf16(A[1][mt], Bh, a, 0, 0, 0);
        a = __builtin_amdgcn_mfma_f32_16x16x32_bf16(A[2][mt], Bh, a, 0, 0, 0);
        a = __builtin_amdgcn_mfma_f32_16x16x32_bf16(A[0][mt], Bl, a, 0, 0, 0);
        a = __builtin_amdgcn_mfma_f32_16x16x32_bf16(A[1][mt], Bl, a, 0, 0, 0);
        a = __builtin_amdgcn_mfma_f32_16x16x32_bf16(A[2][mt], Bl, a, 0, 0, 0);
        a = __builtin_amdgcn_mfma_f32_16x16x32_bf16(A[0][mt], Bll, a, 0, 0, 0);
        a = __builtin_amdgcn_mfma_f32_16x16x32_bf16(A[1][mt], Bll, a, 0, 0, 0);
        acc[tile][mt] = a;
      }
    }
#pragma unroll
    for (int mt = 0; mt < 4; ++mt)
#pragma unroll
      for (int rp = 0; rp < 2; ++rp) {
        float hp[2][2];
#pragma unroll
        for (int tile = 0; tile < 2; ++tile)
#pragma unroll
          for (int e = 0; e < 2; ++e) {
            int reg = rp * 2 + e;
            float xv = fmaf(acc[tile][mt][reg], scr[mt][reg], shr[mt][reg]);
            float spk;
            LIF_STEP(v[tile][mt][reg], xv, spk);
            hp[tile][e] = spk + __shfl_xor(spk, 1);
          }
        int tw = xl & 1;
        float h0 = tw ? hp[1][0] : hp[0][0];
        float h1 = tw ? hp[1][1] : hp[0][1];
        unsigned u = (unsigned)f2bf(h0) | ((unsigned)f2bf(h1) << 16);
        int pp = tw * 8 + (xl >> 1);
        *(unsigned*)&shout[(wave * 16 + pp) * 72 + mt * 16 + q * 4 + rp * 2] = u;
      }
    __syncthreads();
    {
      int cg = tid >> 5, py_l = (tid >> 4) & 1, px = tid & 15;
      uint4 ua = *(const uint4*)&shout[((2 * py_l) * 16 + px) * 72 + cg * 8];
      uint4 ub = *(const uint4*)&shout[((2 * py_l + 1) * 16 + px) * 72 + cg * 8];
      const unsigned* pa = (const unsigned*)&ua;
      const unsigned* pb = (const unsigned*)&ub;
      unsigned o[4];
#pragma unroll
      for (int e = 0; e < 4; ++e) {
        float a0 = bf2f((unsigned short)(pa[e] & 0xffffu)), a1 = bf2f((unsigned short)(pa[e] >> 16));
        float b0 = bf2f((unsigned short)(pb[e] & 0xffffu)), b1 = bf2f((unsigned short)(pb[e] >> 16));
        o[e] = (unsigned)f2bf(0.25f * (a0 + b0)) | ((unsigned)f2bf(0.25f * (a1 + b1)) << 16);
      }
      int py = yq * 2 + py_l;
      *(uint4*)(pool1 + (size_t)tb * 16384 + cg * 2048 + (py * 16 + px) * 8) =
          make_uint4(o[0], o[1], o[2], o[3]);
    }
  }
}

// ---- conv2 helpers ----
__device__ __forceinline__ void c2_load_a(const unsigned short* __restrict__ A2, int kc,
                                          int m0, int xl, int q, short8 (&a)[2][3]) {
#pragma unroll
  for (int mt = 0; mt < 2; ++mt) {
    int aoff = ((kc * 128 + m0 + mt * 16 + xl) * 4 + q) * 8;
    a[mt][0] = *(const short8*)(A2 + aoff);
    a[mt][1] = *(const short8*)(A2 + 73728 + aoff);
    a[mt][2] = *(const short8*)(A2 + 147456 + aoff);
  }
}
__device__ __forceinline__ void c2_step8(const unsigned short* __restrict__ simg, int kc,
                                         int xl, int q, short8 (&a)[2][3], f32x4 (&acc)[2][8]) {
  int tap = kc >> 1;
  int dy = tap / 3, dx = tap - dy * 3;
  int cgq = (kc & 1) * 4 + q;
#pragma unroll
  for (int yl = 0; yl < 8; ++yl) {
    int baddr = (((yl + dy) * 8 + cgq) * 18 + (xl + dx)) * 8;
    short8 bb = *(const short8*)(simg + baddr);
#pragma unroll
    for (int mt = 0; mt < 2; ++mt) {
      acc[mt][yl] = __builtin_amdgcn_mfma_f32_16x16x32_bf16(a[mt][0], bb, acc[mt][yl], 0, 0, 0);
      acc[mt][yl] = __builtin_amdgcn_mfma_f32_16x16x32_bf16(a[mt][1], bb, acc[mt][yl], 0, 0, 0);
      acc[mt][yl] = __builtin_amdgcn_mfma_f32_16x16x32_bf16(a[mt][2], bb, acc[mt][yl], 0, 0, 0);
    }
  }
}

// ---- conv2 (MFMA, single pass): stats + fp32 preact store. (validated R11) ----
__global__ __launch_bounds__(256, 2) void conv2_store_mfma(const unsigned short* __restrict__ pool1,
    const unsigned short* __restrict__ A2, float* __restrict__ preact, float* __restrict__ s2p) {
  int bx = blockIdx.x;
  int tb = bx >> 1, half = bx & 1;
  int sp = bx & 63;
  __shared__ unsigned short simg[10 * 8 * 18 * 8];
  int tid = threadIdx.x;
  const unsigned* src = (const unsigned*)(pool1 + (size_t)tb * 16384);
  unsigned* dstw = (unsigned*)simg;
  for (int i = tid; i < 5760; i += 256) {
    int cp = i & 3, rest = i >> 2;
    int jj = rest / 18, xx = rest - jj * 18;
    int cg = jj & 7, row_l = jj >> 3;
    int yi = half * 8 - 1 + row_l, gx = xx - 1;
    unsigned val = 0u;
    if ((unsigned)yi < 16u && (unsigned)gx < 16u)
      val = src[cg * 1024 + yi * 64 + gx * 4 + cp];
    dstw[i] = val;
  }
  __syncthreads();

  int wave = tid >> 6, lane = tid & 63;
  int xl = lane & 15, q = lane >> 4;
  int m0 = wave * 32;
  f32x4 acc[2][8];
#pragma unroll
  for (int mt = 0; mt < 2; ++mt)
#pragma unroll
    for (int yl = 0; yl < 8; ++yl) acc[mt][yl] = (f32x4){0.f, 0.f, 0.f, 0.f};

  short8 aA[2][3], aB[2][3];
  c2_load_a(A2, 0, m0, xl, q, aA);
#pragma unroll 1
  for (int kc = 0; kc < 18; kc += 2) {
    c2_load_a(A2, kc + 1, m0, xl, q, aB);
    c2_step8(simg, kc, xl, q, aA, acc);
    if (kc + 2 < 18) c2_load_a(A2, kc + 2, m0, xl, q, aA);
    c2_step8(simg, kc + 1, xl, q, aB, acc);
  }

  float* pre = preact + (size_t)tb * 32768;
#pragma unroll
  for (int mt = 0; mt < 2; ++mt)
#pragma unroll
    for (int reg = 0; reg < 4; ++reg) {
      int co = m0 + mt * 16 + q * 4 + reg;
      float s1 = 0.f, s2 = 0.f;
#pragma unroll
      for (int yl = 0; yl < 8; ++yl) {
        float val = acc[mt][yl][reg];
        int row = half * 8 + yl;
        pre[(row * 128 + co) * 16 + xl] = val;
        s1 += val; s2 = fmaf(val, val, s2);
      }
#pragma unroll
      for (int off = 1; off < 16; off <<= 1) {
        s1 += __shfl_xor(s1, off); s2 += __shfl_xor(s2, off);
      }
      if (xl == 0) {
        atomicAdd(&s2p[sp * 256 + co], s1);
        atomicAdd(&s2p[sp * 256 + 128 + co], s2);
      }
    }
}

// ---- BN2-finalize (inlined) + LIF + pool over stored preact. (R12, kept) ----
__global__ __launch_bounds__(256) void bn2_lif_pool(const float* __restrict__ pre,
    const float* __restrict__ s2p, const float* __restrict__ g, const float* __restrict__ bb_,
    unsigned short* __restrict__ pool2) {
  int b = blockIdx.x >> 3, py = blockIdx.x & 7;
  int tid = threadIdx.x;
  int co = tid >> 1, half = tid & 1;
  __shared__ unsigned short shout[8 * 136];
  __shared__ float scsh[256];
  if (tid < 128) {
    int c = tid;
    float t1 = 0.f, t2 = 0.f;
#pragma unroll 8
    for (int sp = 0; sp < 64; ++sp) {
      t1 += s2p[sp * 256 + c];
      t2 += s2p[sp * 256 + 128 + c];
    }
    float mean = t1 * (1.0f / 262144.0f);
    float var = fmaxf(t2 * (1.0f / 262144.0f) - mean * mean, 0.0f);
    float rstd = rsqrtf(var + 1e-5f);
    float sc = g[c] * rstd;
    scsh[c] = sc;
    scsh[128 + c] = fmaf(-mean, sc, bb_[c]);
  }
  __syncthreads();
  float sc = scsh[co], sh = scsh[128 + co];
  float v[4][4];
#pragma unroll
  for (int p = 0; p < 4; ++p)
#pragma unroll
    for (int e = 0; e < 4; ++e) v[p][e] = 0.f;

#pragma unroll 1
  for (int t = 0; t < 8; ++t) {
    const float* base = pre + ((size_t)((t * 128 + b) * 16 + 2 * py)) * 2048 + co * 16 + half * 8;
    __syncthreads();
    float4 r0a = *(const float4*)(base);
    float4 r0b = *(const float4*)(base + 4);
    float4 r1a = *(const float4*)(base + 2048);
    float4 r1b = *(const float4*)(base + 2048 + 4);
    float p00[4] = {r0a.x, r0a.z, r0b.x, r0b.z};
    float p01[4] = {r0a.y, r0a.w, r0b.y, r0b.w};
    float p10[4] = {r1a.x, r1a.z, r1b.x, r1b.z};
    float p11[4] = {r1a.y, r1a.w, r1b.y, r1b.w};
#pragma unroll
    for (int p = 0; p < 4; ++p) {
      float s00, s01, s10, s11, xv;
      xv = fmaf(p00[p], sc, sh); LIF_STEP(v[p][0], xv, s00);
      xv = fmaf(p01[p], sc, sh); LIF_STEP(v[p][1], xv, s01);
      xv = fmaf(p10[p], sc, sh); LIF_STEP(v[p][2], xv, s10);
      xv = fmaf(p11[p], sc, sh); LIF_STEP(v[p][3], xv, s11);
      shout[(half * 4 + p) * 136 + co] = f2bf(0.25f * (s00 + s01 + s10 + s11));
    }
    __syncthreads();
    {
      int s_l = tid >> 5, ci4 = (tid & 31) * 4;
      uint2 vv = *(const uint2*)&shout[s_l * 136 + ci4];
      *(uint2*)(pool2 + ((size_t)(t * 128 + b) * 64 + py * 8 + s_l) * 128 + ci4) = vv;
    }
  }
}

// ---- fc1 (MFMA): partial[kb][o 256][tb 1024], split-K=16, 2 kc/barrier. (validated R11) ----
__global__ __launch_bounds__(256, 2) void fc1_mfma(const unsigned short* __restrict__ pool2,
    const unsigned short* __restrict__ B1, float* __restrict__ partial) {
  int bx = blockIdx.x;
  int t_o = bx & 1, tbt = (bx >> 1) & 15, kb = bx >> 5;
  int tid = threadIdx.x, wave = tid >> 6, lane = tid & 63;
  int xl = lane & 15, q = lane >> 4;
  int m0 = t_o * 128 + wave * 32;
  int n0 = tbt * 64;
  __shared__ unsigned short sB[2][64 * 42];
  f32x4 acc[2][4];
#pragma unroll
  for (int mt = 0; mt < 2; ++mt)
#pragma unroll
    for (int nt = 0; nt < 4; ++nt) acc[mt][nt] = (f32x4){0.f, 0.f, 0.f, 0.f};

#pragma unroll 1
  for (int kc0 = 0; kc0 < 16; kc0 += 2) {
    int kc = kb * 16 + kc0;
    __syncthreads();
    {
      int tb_l = tid >> 2, kq = tid & 3;
      const unsigned short* srcp = pool2 + (size_t)(n0 + tb_l) * 8192 + kc * 32 + kq * 8;
      uint4 v0 = *(const uint4*)(srcp);
      uint4 v1 = *(const uint4*)(srcp + 32);
      *(uint4*)(sB[0] + tb_l * 42 + kq * 8) = v0;
      *(uint4*)(sB[1] + tb_l * 42 + kq * 8) = v1;
    }
    __syncthreads();
#pragma unroll
    for (int sub = 0; sub < 2; ++sub) {
      int kcs = kc + sub;
      short8 a[2][3];
#pragma unroll
      for (int mt = 0; mt < 2; ++mt) {
        int aoff = ((kcs * 256 + m0 + mt * 16 + xl) * 4 + q) * 8;
        a[mt][0] = *(const short8*)(B1 + aoff);
        a[mt][1] = *(const short8*)(B1 + 2097152 + aoff);
        a[mt][2] = *(const short8*)(B1 + 4194304 + aoff);
      }
#pragma unroll
      for (int nt = 0; nt < 4; ++nt) {
        short8 bb = *(const short8*)(sB[sub] + (nt * 16 + xl) * 42 + q * 8);
#pragma unroll
        for (int mt = 0; mt < 2; ++mt) {
          acc[mt][nt] = __builtin_amdgcn_mfma_f32_16x16x32_bf16(a[mt][0], bb, acc[mt][nt], 0, 0, 0);
          acc[mt][nt] = __builtin_amdgcn_mfma_f32_16x16x32_bf16(a[mt][1], bb, acc[mt][nt], 0, 0, 0);
          acc[mt][nt] = __builtin_amdgcn_mfma_f32_16x16x32_bf16(a[mt][2], bb, acc[mt][nt], 0, 0, 0);
        }
      }
    }
  }
#pragma unroll
  for (int mt = 0; mt < 2; ++mt)
#pragma unroll
    for (int nt = 0; nt < 4; ++nt)
#pragma unroll
      for (int reg = 0; reg < 4; ++reg) {
        int o = m0 + mt * 16 + q * 4 + reg;
        partial[((size_t)kb * 256 + o) * 1024 + n0 + nt * 16 + xl] = acc[mt][nt][reg];
      }
}

// ---- reduce partials + LIF -> fc1 spikes [t][b][o]. (validated, coalesced) ----
__global__ __launch_bounds__(256) void reduce_lif(const float* __restrict__ partial, float* __restrict__ fs) {
  int idx = blockIdx.x * 256 + threadIdx.x;
  int o = idx >> 7, b = idx & 127;
  float v = 0.f;
#pragma unroll 1
  for (int t = 0; t < 8; ++t) {
    float xv = 0.f;
#pragma unroll
    for (int kb = 0; kb < 16; ++kb)
      xv += partial[((size_t)kb * 256 + o) * 1024 + t * 128 + b];
    float s;
    LIF_STEP(v, xv, s);
    fs[t * 32768 + b * 256 + o] = s;
  }
}

__global__ __launch_bounds__(256) void fc2_kernel(const float* __restrict__ fs, const float* __restrict__ w,
                                                  const float* __restrict__ bias, float* __restrict__ outp) {
  int tb = blockIdx.x;
  __shared__ float sv[256];
  int tid = threadIdx.x;
  sv[tid] = fs[tb * 256 + tid];
  __syncthreads();
  if (tid < 10) {
    float a = bias[tid];
    const float* wr = w + tid * 256;
#pragma unroll 8
    for (int o = 0; o < 256; ++o) a = fmaf(sv[o], wr[o], a);
    outp[tb * 10 + tid] = a;
  }
}

extern "C" void kernel_launch(void* const* d_in, const int* in_sizes, int n_in,
                              void* d_out, int out_size, void* d_ws, size_t ws_size,
                              hipStream_t stream) {
  (void)in_sizes; (void)n_in; (void)out_size; (void)ws_size;
  const float* x_seq   = (const float*)d_in[0];
  const float* conv1_w = (const float*)d_in[1];
  const float* bn1_g   = (const float*)d_in[2];
  const float* bn1_b   = (const float*)d_in[3];
  const float* conv2_w = (const float*)d_in[4];
  const float* bn2_g   = (const float*)d_in[5];
  const float* bn2_b   = (const float*)d_in[6];
  const float* fc1_w   = (const float*)d_in[7];
  const float* fc2_w   = (const float*)d_in[8];
  const float* fc2_b   = (const float*)d_in[9];
  float* out = (float*)d_out;
  float* ws  = (float*)d_ws;

  unsigned short* pool1 = (unsigned short*)(ws + OFF_POOL1);
  float* fc1_part = ws + OFF_POOL1;              // pool1 dead after conv2_store
  unsigned short* pool2 = (unsigned short*)(ws + OFF_POOL2);
  float* preact  = ws + OFF_PRE;
  float* fc1_s   = ws + OFF_FC1S;
  unsigned short* A2 = (unsigned short*)(ws + OFF_A2);
  unsigned short* B1 = (unsigned short*)(ws + OFF_B1);
  unsigned short* A1 = (unsigned short*)(ws + OFF_A1);
  float* st      = ws + OFF_STATS;
  float* s1p    = st;            // [64 sp][2][64]
  float* s2p    = st + 8192;     // [64 sp][2][128]

  prep_all<<<776, 256, 0, stream>>>(conv1_w, conv2_w, fc1_w, st, A1, A2, B1);
  conv1_pass1_mfma<<<1024, 256, 0, stream>>>(x_seq, A1, s1p);
  conv1_fused_mfma<<<1024, 256, 0, stream>>>(x_seq, A1, s1p, bn1_g, bn1_b, pool1);
  conv2_store_mfma<<<2048, 256, 0, stream>>>(pool1, A2, preact, s2p);
  bn2_lif_pool<<<1024, 256, 0, stream>>>(preact, s2p, bn2_g, bn2_b, pool2);
  fc1_mfma<<<512, 256, 0, stream>>>(pool2, B1, fc1_part);
  reduce_lif<<<128, 256, 0, stream>>>(fc1_part, fc1_s);
  fc2_kernel<<<1024, 256, 0, stream>>>(fc1_s, fc2_w, fc2_b, out);
}